// Round 5
// baseline (651.112 us; speedup 1.0000x reference)
//
#include <hip/hip_runtime.h>
#include <math.h>

#define Bb 32
#define Pp 1024
#define Nn 1024

typedef unsigned short u16;
typedef __bf16 bf16x8 __attribute__((ext_vector_type(8)));
typedef float f32x4 __attribute__((ext_vector_type(4)));
typedef u16 us8 __attribute__((ext_vector_type(8)));

#define MFMA __builtin_amdgcn_mfma_f32_16x16x32_bf16

static constexpr float INV_SQRT_E = 0.08838834764831845f;  // 1/sqrt(128)

__device__ __forceinline__ bf16x8 asbf(us8 v) { return __builtin_bit_cast(bf16x8, v); }

// RTN split: x ~= hi + lo to ~2^-17 rel (used for precomputed planes / aft)
__device__ __forceinline__ void bsplit(float x, u16& h, u16& l) {
  unsigned u = __float_as_uint(x);
  unsigned r = u + 0x7FFF + ((u >> 16) & 1);
  h = (u16)(r >> 16);
  float hf = __uint_as_float((unsigned)h << 16);
  float lof = x - hf;
  unsigned u2 = __float_as_uint(lof);
  unsigned r2 = u2 + 0x7FFF + ((u2 >> 16) & 1);
  l = (u16)(r2 >> 16);
}

// cheap trunc split: x ~= hi + lo to ~2^-16 rel, ~5 VALU ops (hot A-path)
__device__ __forceinline__ void tsplit(float x, u16& h, u16& l) {
  unsigned u = __float_as_uint(x);
  h = (u16)(u >> 16);
  float lof = x - __uint_as_float(u & 0xFFFF0000u);
  l = (u16)(__float_as_uint(lof) >> 16);
}

__device__ __forceinline__ float fast_tanh(float x) {
  float ax = fabsf(x);
  float t = __expf(-2.0f * ax);
  float r = (1.0f - t) / (1.0f + t);
  return copysignf(r, x);
}

// ---------------- K0: transposed split weight planes ----------------
__global__ __launch_bounds__(256) void prep_weights(
    const float* __restrict__ Wq1, const float* __restrict__ Wq2,
    const float* __restrict__ Wql, const float* __restrict__ Wk,
    const float* __restrict__ Wv, u16* __restrict__ wcat_hi, u16* __restrict__ wcat_lo,
    u16* __restrict__ wkv_hi, u16* __restrict__ wkv_lo) {
  int t = threadIdx.x;
  if (blockIdx.x == 0) {
    for (int i = t; i < 128 * 384; i += 256) {
      int c = i / 384, k = i % 384;
      float v = (k < 128) ? Wq1[k * 128 + c]
                          : (k < 256) ? Wq2[(k - 128) * 128 + c] : Wql[(k - 256) * 128 + c];
      u16 h, l;
      bsplit(v, h, l);
      wcat_hi[i] = h;
      wcat_lo[i] = l;
    }
  } else {
    for (int i = t; i < 256 * 128; i += 256) {
      int c = i >> 7, k = i & 127;
      float v = (c < 128) ? Wk[k * 128 + c] : Wv[k * 128 + (c - 128)];
      u16 h, l;
      bsplit(v, h, l);
      wkv_hi[i] = h;
      wkv_lo[i] = l;
    }
  }
}

// ---------------- K1: k/v GEMM (split MFMA) -> ekkT planes + nodesP planes ----------------
// block mapping mirrors main_kernel so each ekkT slab is produced on its consuming XCD
__global__ __launch_bounds__(256, 1) void kv_prep(
    const float* __restrict__ nodes, const u16* __restrict__ wkv_hi,
    const u16* __restrict__ wkv_lo, u16* __restrict__ ekkT_hi, u16* __restrict__ ekkT_lo,
    u16* __restrict__ nodesP_hi, u16* __restrict__ nodesP_lo) {
  __shared__ u16 a_hi[32 * 136], a_lo[32 * 136];
  __shared__ float kvbuf[32 * 264];
  const int t = threadIdx.x;
  const int xcd = blockIdx.x & 7, jj = blockIdx.x >> 3;
  const int b = xcd * 4 + (jj >> 5);
  const int n0 = (jj & 31) * 32;
  for (int i = t; i < 4096; i += 256) {
    int n = i >> 7, d = i & 127;
    float v = nodes[((long)(b * 1024 + n0 + n)) * 128 + d];
    u16 h, l;
    bsplit(v, h, l);
    a_hi[n * 136 + d] = h;
    a_lo[n * 136 + d] = l;
  }
  __syncthreads();
  const int lane = t & 63, w = t >> 6;
  const int lr = lane & 15, lg = lane >> 4;
  f32x4 acc0[2][4] = {}, acc1[2][4] = {};
#pragma unroll
  for (int ks = 0; ks < 4; ++ks) {
    us8 ah[2], al[2];
#pragma unroll
    for (int mt = 0; mt < 2; ++mt) {
      int ro = (lr + 16 * mt) * 136 + ks * 32 + lg * 8;
      ah[mt] = *(const us8*)&a_hi[ro];
      al[mt] = *(const us8*)&a_lo[ro];
    }
    us8 bh[4], bl[4];
#pragma unroll
    for (int cc = 0; cc < 4; ++cc) {
      long off = (long)((w * 4 + cc) * 16 + lr) * 128 + ks * 32 + lg * 8;
      bh[cc] = *(const us8*)&wkv_hi[off];
      bl[cc] = *(const us8*)&wkv_lo[off];
    }
#pragma unroll
    for (int mt = 0; mt < 2; ++mt)
#pragma unroll
      for (int cc = 0; cc < 4; ++cc) {
        acc0[mt][cc] = MFMA(asbf(ah[mt]), asbf(bh[cc]), acc0[mt][cc], 0, 0, 0);
        acc1[mt][cc] = MFMA(asbf(al[mt]), asbf(bh[cc]), acc1[mt][cc], 0, 0, 0);
        acc1[mt][cc] = MFMA(asbf(ah[mt]), asbf(bl[cc]), acc1[mt][cc], 0, 0, 0);
      }
  }
#pragma unroll
  for (int mt = 0; mt < 2; ++mt)
#pragma unroll
    for (int cc = 0; cc < 4; ++cc) {
      int c = (w * 4 + cc) * 16 + lr;
#pragma unroll
      for (int r = 0; r < 4; ++r)
        kvbuf[(lg * 4 + r + 16 * mt) * 264 + c] = acc0[mt][cc][r] + acc1[mt][cc][r];
    }
  __syncthreads();
#pragma unroll
  for (int jo = 0; jo < 4; ++jo) {
    int j = jo * 64 + (t >> 2);
    int i4 = t & 3;
    int kcol = (j < 128) ? j : (j - 128);
    us8 h8, l8;
#pragma unroll
    for (int jq = 0; jq < 8; ++jq) {
      int n = i4 * 8 + jq;
      float kv = kvbuf[n * 264 + kcol];
      float ek = __expf(kv);
      float val = (j < 128) ? ek * kvbuf[n * 264 + j + 128] : ek;
      u16 h, l;
      bsplit(val, h, l);
      h8[jq] = h;
      l8[jq] = l;
    }
    long o = ((long)(b * 256 + j)) * 1024 + n0 + i4 * 8;
    *(us8*)&ekkT_hi[o] = h8;
    *(us8*)&ekkT_lo[o] = l8;
  }
  {
    int pl = t >> 7, r = t & 127;
    int dgrp = r >> 3, nb = r & 7;
    const u16* src = pl ? a_lo : a_hi;
    u16* dst = pl ? nodesP_lo : nodesP_hi;
#pragma unroll
    for (int i = 0; i < 4; ++i) {
      int n = nb + 8 * i;
      us8 v = *(const us8*)&src[n * 136 + dgrp * 8];
      *(us8*)&dst[(((long)(b * 16 + dgrp)) * 1024 + n0 + n) * 8] = v;
    }
  }
}

// ---------------- main fused kernel: 32 p-rows per block, 512 threads ----------------
// Barrier-free P1/P2: A-fragments computed in-register from global loads.
// Wave (rg,cg): rows rg*16..+16, num cols cg*32..+32 paired with den cols 128+cg*32..+32.
__global__ __launch_bounds__(512, 4) void main_kernel(
    const float* __restrict__ q1m, const float* __restrict__ q2m,
    const float* __restrict__ lnm, const float* __restrict__ loadv,
    const float* __restrict__ leftv, const float* __restrict__ cdist,
    const float* __restrict__ ninf, const float* __restrict__ Wql,
    const u16* __restrict__ wcat_hi, const u16* __restrict__ wcat_lo,
    const u16* __restrict__ ekkT_hi, const u16* __restrict__ ekkT_lo,
    const u16* __restrict__ nodesP_hi, const u16* __restrict__ nodesP_lo,
    float* __restrict__ out, const float* __restrict__ logs,
    const float* __restrict__ aal, const float* __restrict__ pal) {
  __shared__ u16 aft_hi[32 * 136];
  __shared__ u16 aft_lo[32 * 136];
  __shared__ float sbuf[32 * 264];
  __shared__ float psum[32 * 4];
  __shared__ float invb[32];

  const int t = threadIdx.x;
  const int lane = t & 63, w = t >> 6;
  const int lr = lane & 15, lg = lane >> 4;
  const int rg = w & 1, cg = w >> 1;
  const int xcd = blockIdx.x & 7, j = blockIdx.x >> 3;
  const int b = xcd * 4 + (j >> 5);
  const int p0 = (j & 31) * 32;
  const long bp = (long)b * Pp + p0;
  const float ls = logs[0];
  const float c1 = ls * aal[0], c2 = ls * pal[0];

  const long arowg = bp + rg * 16 + lr;  // global row for A-fragments (row = lr)

  // ================= P1: q GEMM (K=384), A in-reg, barrier-free =================
  f32x4 qacc[2] = {};
#pragma unroll 2
  for (int s = 0; s < 12; ++s) {
    const float* __restrict__ src = (s < 4) ? q1m : (s < 8) ? q2m : lnm;
    long ao = arowg * 128 + (s & 3) * 32 + lg * 8;
    float4 a0 = *(const float4*)&src[ao];
    float4 a1 = *(const float4*)&src[ao + 4];
    float av[8] = {a0.x, a0.y, a0.z, a0.w, a1.x, a1.y, a1.z, a1.w};
    us8 ah, al;
#pragma unroll
    for (int jq = 0; jq < 8; ++jq) {
      u16 hh, ll;
      tsplit(av[jq], hh, ll);
      ah[jq] = hh;
      al[jq] = ll;
    }
#pragma unroll
    for (int cf = 0; cf < 2; ++cf) {
      int c = cg * 32 + cf * 16 + lr;
      us8 bh = *(const us8*)&wcat_hi[c * 384 + s * 32 + lg * 8];
      us8 bl = *(const us8*)&wcat_lo[c * 384 + s * 32 + lg * 8];
      qacc[cf] = MFMA(asbf(ah), asbf(bh), qacc[cf], 0, 0, 0);
      qacc[cf] = MFMA(asbf(al), asbf(bh), qacc[cf], 0, 0, 0);
      qacc[cf] = MFMA(asbf(ah), asbf(bl), qacc[cf], 0, 0, 0);
    }
  }
  float sigv[2][4];
#pragma unroll
  for (int cf = 0; cf < 2; ++cf) {
    int c = cg * 32 + cf * 16 + lr;
    float wl1 = Wql[128 * 128 + c], wl2 = Wql[129 * 128 + c];
#pragma unroll
    for (int r = 0; r < 4; ++r) {
      int row = rg * 16 + lg * 4 + r;
      float qv = qacc[cf][r] + loadv[bp + row] * wl1 + leftv[bp + row] * wl2;
      sigv[cf][r] = 1.0f / (1.0f + __expf(-qv));
    }
  }

  // ================= P2: [num|den] = e_bias @ ekkT^T, barrier-free =================
  // cf 0,1 -> num cols cg*32+cf*16 ; cf 2,3 -> den cols 128+cg*32+(cf-2)*16
  f32x4 acc2[4] = {};
  long bbase[4];
#pragma unroll
  for (int cf = 0; cf < 4; ++cf) {
    int ccol = ((cf < 2) ? (cg * 32 + cf * 16) : (128 + cg * 32 + (cf - 2) * 16)) + lr;
    bbase[cf] = ((long)(b * 256 + ccol)) * 1024;
  }
#pragma unroll 2
  for (int s = 0; s < 32; ++s) {
    long ao = arowg * 1024 + s * 32 + lg * 8;
    float4 d0 = *(const float4*)&cdist[ao];
    float4 d1 = *(const float4*)&cdist[ao + 4];
    float4 f0 = *(const float4*)&ninf[ao];
    float4 f1 = *(const float4*)&ninf[ao + 4];
    float dv[8] = {d0.x, d0.y, d0.z, d0.w, d1.x, d1.y, d1.z, d1.w};
    float nv[8] = {f0.x, f0.y, f0.z, f0.w, f1.x, f1.y, f1.z, f1.w};
    us8 ah, al;
#pragma unroll
    for (int jq = 0; jq < 8; ++jq) {
      float eb = __expf(fmaf(-c1, dv[jq], nv[jq]));
      u16 hh, ll;
      tsplit(eb, hh, ll);
      ah[jq] = hh;
      al[jq] = ll;
    }
#pragma unroll
    for (int cf = 0; cf < 4; ++cf) {
      us8 bh = *(const us8*)&ekkT_hi[bbase[cf] + s * 32 + lg * 8];
      us8 bl = *(const us8*)&ekkT_lo[bbase[cf] + s * 32 + lg * 8];
      acc2[cf] = MFMA(asbf(ah), asbf(bh), acc2[cf], 0, 0, 0);
      acc2[cf] = MFMA(asbf(al), asbf(bh), acc2[cf], 0, 0, 0);
      acc2[cf] = MFMA(asbf(ah), asbf(bl), acc2[cf], 0, 0, 0);
    }
  }

  // ================= P3: AFT lane-local (num/den same lane), -> split LDS =========
#pragma unroll
  for (int cf = 0; cf < 2; ++cf) {
#pragma unroll
    for (int r = 0; r < 4; ++r) {
      float aftv = sigv[cf][r] * (acc2[cf][r] / (acc2[cf + 2][r] + 1e-20f));
      u16 h, l;
      bsplit(aftv, h, l);
      int row = rg * 16 + lg * 4 + r;
      int c = cg * 32 + cf * 16 + lr;
      aft_hi[row * 136 + c] = h;
      aft_lo[row * 136 + c] = l;
    }
  }
  __syncthreads();

  // ================= P4: score = AFT @ nodes^T; wave cols cg*256..+256 =============
  f32x4 sacc[16] = {};
#pragma unroll
  for (int ks = 0; ks < 4; ++ks) {
    us8 ah = *(const us8*)&aft_hi[(rg * 16 + lr) * 136 + ks * 32 + lg * 8];
    us8 al = *(const us8*)&aft_lo[(rg * 16 + lr) * 136 + ks * 32 + lg * 8];
    long nb = ((long)(b * 16 + ks * 4 + lg)) * 1024;
#pragma unroll
    for (int cf = 0; cf < 16; ++cf) {
      long o = (nb + cg * 256 + cf * 16 + lr) * 8;
      us8 bh = *(const us8*)&nodesP_hi[o];
      us8 bl = *(const us8*)&nodesP_lo[o];
      sacc[cf] = MFMA(asbf(ah), asbf(bh), sacc[cf], 0, 0, 0);
      sacc[cf] = MFMA(asbf(al), asbf(bh), sacc[cf], 0, 0, 0);
      sacc[cf] = MFMA(asbf(ah), asbf(bl), sacc[cf], 0, 0, 0);
    }
  }

  // ================= P5a: scale + dist + tanh-clip + exp (in regs) ================
  float rs[4] = {};
#pragma unroll
  for (int cf = 0; cf < 16; ++cf) {
    int n = cg * 256 + cf * 16 + lr;
#pragma unroll
    for (int r = 0; r < 4; ++r) {
      int row = rg * 16 + lg * 4 + r;
      long off = (bp + row) * (long)Nn + n;
      float sv = fmaf(sacc[cf][r], INV_SQRT_E, -c2 * cdist[off]);
      float e = __expf(10.0f * fast_tanh(sv) + ninf[off]);
      sacc[cf][r] = e;
      rs[r] += e;
    }
  }
  // P5b: row sums across lr lanes (cols), then across cg via psum
#pragma unroll
  for (int r = 0; r < 4; ++r) {
    float v = rs[r];
    v += __shfl_xor(v, 1);
    v += __shfl_xor(v, 2);
    v += __shfl_xor(v, 4);
    v += __shfl_xor(v, 8);
    rs[r] = v;
  }
  if (lr == 0) {
#pragma unroll
    for (int r = 0; r < 4; ++r) psum[(rg * 16 + lg * 4 + r) * 4 + cg] = rs[r];
  }
  __syncthreads();
  if (t < 32)
    invb[t] = 1.0f / (psum[t * 4] + psum[t * 4 + 1] + psum[t * 4 + 2] + psum[t * 4 + 3]);
  __syncthreads();

  // ================= P5c: 4 rounds of LDS-staged, fully-coalesced stores ==========
#pragma unroll 1
  for (int c = 0; c < 4; ++c) {
    if (cg == c) {
#pragma unroll
      for (int cf = 0; cf < 16; ++cf)
#pragma unroll
        for (int r = 0; r < 4; ++r) {
          int row = rg * 16 + lg * 4 + r;
          sbuf[row * 264 + cf * 16 + lr] = sacc[cf][r] * invb[row];
        }
    }
    __syncthreads();
    {
      int row = t >> 4, cq = t & 15;
      long ro = (bp + row) * (long)Nn + c * 256 + cq * 16;
#pragma unroll
      for (int i = 0; i < 4; ++i)
        *(float4*)&out[ro + i * 4] = *(const float4*)&sbuf[row * 264 + cq * 16 + i * 4];
    }
    __syncthreads();
  }
}

extern "C" void kernel_launch(void* const* d_in, const int* in_sizes, int n_in,
                              void* d_out, int out_size, void* d_ws, size_t ws_size,
                              hipStream_t stream) {
  const float* nodes = (const float*)d_in[0];
  const float* q1m = (const float*)d_in[1];
  const float* q2m = (const float*)d_in[2];
  const float* lnm = (const float*)d_in[3];
  const float* loadv = (const float*)d_in[4];
  const float* leftv = (const float*)d_in[5];
  const float* cdist = (const float*)d_in[6];
  const float* logs = (const float*)d_in[7];
  const float* ninf = (const float*)d_in[8];
  const float* Wq1 = (const float*)d_in[9];
  const float* Wq2 = (const float*)d_in[10];
  const float* Wql = (const float*)d_in[11];
  const float* Wk = (const float*)d_in[12];
  const float* Wv = (const float*)d_in[13];
  const float* aalpha = (const float*)d_in[14];
  const float* palpha = (const float*)d_in[15];

  char* ws = (char*)d_ws;
  u16* ekkT_hi = (u16*)ws;                            // 16 MB
  u16* ekkT_lo = (u16*)(ws + (16u << 20));            // 16 MB
  u16* nodesP_hi = (u16*)(ws + (32u << 20));          // 8 MB
  u16* nodesP_lo = (u16*)(ws + (40u << 20));          // 8 MB
  u16* wcat_hi = (u16*)(ws + (48u << 20));
  u16* wcat_lo = wcat_hi + 128 * 384;
  u16* wkv_hi = wcat_lo + 128 * 384;
  u16* wkv_lo = wkv_hi + 256 * 128;

  prep_weights<<<2, 256, 0, stream>>>(Wq1, Wq2, Wql, Wk, Wv, wcat_hi, wcat_lo, wkv_hi, wkv_lo);
  kv_prep<<<Bb * Nn / 32, 256, 0, stream>>>(nodes, wkv_hi, wkv_lo, ekkT_hi, ekkT_lo,
                                            nodesP_hi, nodesP_lo);
  main_kernel<<<Bb * Pp / 32, 512, 0, stream>>>(
      q1m, q2m, lnm, loadv, leftv, cdist, ninf, Wql, wcat_hi, wcat_lo, ekkT_hi, ekkT_lo,
      nodesP_hi, nodesP_lo, (float*)d_out, logs, aalpha, palpha);
}